// Round 2
// baseline (243.887 us; speedup 1.0000x reference)
//
#include <hip/hip_runtime.h>

typedef _Float16 f16;
typedef _Float16 f16x8 __attribute__((ext_vector_type(8)));
typedef _Float16 f16x4 __attribute__((ext_vector_type(4)));
typedef float f32x4 __attribute__((ext_vector_type(4)));

#define B_TOT 128
#define T_LEN 512
#define D_DIM 256
#define H_DIM 512

// ---------------- helpers ----------------
__device__ __forceinline__ void gload_lds16(const void* g, void* l) {
  __builtin_amdgcn_global_load_lds(
      (const __attribute__((address_space(1))) void*)g,
      (__attribute__((address_space(3))) void*)l, 16, 0, 0);
}

__device__ __forceinline__ float rcpf(float x) { return __builtin_amdgcn_rcpf(x); }

// ---------------- kernel 1: weight convert + transpose ----------------
// W[k][n] f32 (256x512) -> Wt[n][k] f16 (512x256), 3 weights
__global__ void __launch_bounds__(256) cvt_w(const float* __restrict__ Wr,
                                             const float* __restrict__ Wz,
                                             const float* __restrict__ Wh,
                                             f16* __restrict__ Wt) {
  int idx = blockIdx.x * 256 + threadIdx.x;      // < 3*131072
  int w = idx >> 17;
  int rem = idx & 131071;
  int n = rem >> 8;        // 0..511
  int k = rem & 255;       // 0..255
  const float* W = (w == 0) ? Wr : ((w == 1) ? Wz : Wh);
  Wt[(size_t)w * 131072 + n * 256 + k] = (f16)W[k * 512 + n];
}

// ---------------- kernel 2: x convert f32 -> f16 ----------------
__global__ void __launch_bounds__(256) cvt_x(const float4* __restrict__ in,
                                             f16x4* __restrict__ out) {
  int idx = blockIdx.x * 256 + threadIdx.x;
  float4 v = in[idx];
  f16x4 o;
  o[0] = (f16)v.x; o[1] = (f16)v.y; o[2] = (f16)v.z; o[3] = (f16)v.w;
  out[idx] = o;
}

// ---------------- kernel 3: fused 3-weight GEMM ----------------
// X [M][256] f16, Wt [512][256] f16 (pre-transposed), P stored TRANSPOSED:
// P[bb][h][t] f16  (bb = local batch, t = m & 511)
// tile: BM=128 x (BN=64 per weight), BK=32; 256 threads = 4 waves (2x2)
#define BM 128
#define BN 64
#define BK 32

__global__ void __launch_bounds__(256) brc_gemm3(
    const f16* __restrict__ X,
    const f16* __restrict__ Wr, const f16* __restrict__ Wz, const f16* __restrict__ Wh,
    f16* __restrict__ Pr, f16* __restrict__ Pz, f16* __restrict__ Ph,
    int Mtiles) {
  __shared__ f16 lds[BM * BK + 3 * BN * BK];   // 4096 + 6144 halfs = 20 KiB
  const int tid = threadIdx.x;
  const int wid = tid >> 6, lane = tid & 63;
  const int bid = blockIdx.x;
  const int mt = bid % Mtiles, nt = bid / Mtiles;
  const int m0 = mt * BM, n0 = nt * BN;
  const int wr = wid >> 1, wc = wid & 1;   // 2x2 wave grid: wave tile 64x32

  f32x4 acc[3][4][2] = {};

  for (int kt = 0; kt < 8; ++kt) {
    const int k0 = kt * BK;
    // ---- stage A: 128x32 halfs = 8192B, 2 x 16B per thread ----
#pragma unroll
    for (int c = 0; c < 2; ++c) {
      int o = c * 4096 + wid * 1024 + lane * 16;            // byte offset in tile
      const char* g = (const char*)X + ((size_t)(m0 + (o >> 6))) * 512 + k0 * 2 + (o & 63);
      char* l = (char*)lds + c * 4096 + wid * 1024;         // wave-uniform dest
      gload_lds16(g, l);
    }
    // ---- stage B: 3 x (64x32 halfs = 4096B), 1 x 16B per thread per weight ----
    {
      int o = wid * 1024 + lane * 16;
      size_t goff = ((size_t)(n0 + (o >> 6))) * 512 + k0 * 2 + (o & 63);
      char* l = (char*)lds + 8192 + wid * 1024;             // wave-uniform dest
      gload_lds16((const char*)Wr + goff, l);
      gload_lds16((const char*)Wz + goff, l + 4096);
      gload_lds16((const char*)Wh + goff, l + 8192);
    }
    __syncthreads();

    f16x8 a[4], b[3][2];
#pragma unroll
    for (int mi = 0; mi < 4; ++mi)
      a[mi] = *(const f16x8*)&lds[(wr * 64 + mi * 16 + (lane & 15)) * BK + (lane >> 4) * 8];
#pragma unroll
    for (int w = 0; w < 3; ++w)
#pragma unroll
      for (int ni = 0; ni < 2; ++ni)
        b[w][ni] = *(const f16x8*)&lds[BM * BK + w * (BN * BK) +
                                       (wc * 32 + ni * 16 + (lane & 15)) * BK + (lane >> 4) * 8];
#pragma unroll
    for (int w = 0; w < 3; ++w)
#pragma unroll
      for (int mi = 0; mi < 4; ++mi)
#pragma unroll
        for (int ni = 0; ni < 2; ++ni)
          acc[w][mi][ni] = __builtin_amdgcn_mfma_f32_16x16x32_f16(
              a[mi], b[w][ni], acc[w][mi][ni], 0, 0, 0);
    __syncthreads();
  }

  // ---- epilogue: C/D layout col = lane&15, row = (lane>>4)*4 + r ----
  // rows are consecutive m => consecutive t within one bb (tiles never cross b)
  // store transposed P[bb][h][t] as one f16x4 (8B) per fragment per lane
  const int col = lane & 15;
  const int rbase = (lane >> 4) * 4;
#pragma unroll
  for (int w = 0; w < 3; ++w) {
    f16* P = (w == 0) ? Pr : ((w == 1) ? Pz : Ph);
#pragma unroll
    for (int mi = 0; mi < 4; ++mi) {
      int m = m0 + wr * 64 + mi * 16 + rbase;
      int bbl = m >> 9;
      int t = m & 511;
#pragma unroll
      for (int ni = 0; ni < 2; ++ni) {
        int hcol = n0 + wc * 32 + ni * 16 + col;
        f16x4 v;
#pragma unroll
        for (int r = 0; r < 4; ++r) v[r] = (f16)acc[w][mi][ni][r];
        *(f16x4*)&P[(((size_t)bbl * 512 + hcol) << 9) + t] = v;
      }
    }
  }
}

// ---------------- kernel 4: recurrent scan ----------------
// One thread per (batch, hidden) chain. P is [bb][h][t] so 8 steps = one
// f16x8 load per array. Quad-buffered, 3 groups ahead. rcp instead of div.
__global__ void __launch_bounds__(256) brc_scan(
    const f16* __restrict__ Pr, const f16* __restrict__ Pz, const f16* __restrict__ Ph,
    const float* __restrict__ h0, const float* __restrict__ mr, const float* __restrict__ mz,
    const float* __restrict__ br, const float* __restrict__ bz,
    float* __restrict__ out, int b0) {
  int gid = blockIdx.x * 256 + threadIdx.x;   // 0 .. bc*512-1
  int bb = gid >> 9;
  int i = gid & 511;
  float h = h0[((size_t)(b0 + bb) << 9) + i];
  // fold the tanh/sigmoid argument scalings into per-thread constants:
  // r:  e = exp(2*(pr+br+h*mr))      -> exp(fma(h, 2mr, 2*pr + 2*br))
  // z:  e = exp(-(pz+bz+h*mz))       -> exp(fma(h, -mz, -pz - bz))
  // c:  e = exp(2*(ph + r*h))        -> exp(fma(r, 2h, 2*ph))
  float mrc = 2.0f * mr[i], mzc = -mz[i];
  float br2 = 2.0f * br[i], nbz = -bz[i];
  size_t pbase = ((size_t)gid) << 9;                 // (bb*512 + i) * 512
  const f16* prp = Pr + pbase;
  const f16* pzp = Pz + pbase;
  const f16* php = Ph + pbase;
  float* op = out + (((size_t)(b0 + bb)) << 18) + i;

  f16x8 Ar, Az, Ah, Br_, Bz_, Bh_, Cr, Cz, Ch, Dr, Dz, Dh;

#define LOADG(R, Z, Hh, g)                                              \
  do {                                                                  \
    R  = *(const f16x8*)(prp + ((size_t)(g) << 3));                     \
    Z  = *(const f16x8*)(pzp + ((size_t)(g) << 3));                     \
    Hh = *(const f16x8*)(php + ((size_t)(g) << 3));                     \
  } while (0)

#define STEP8(R, Z, Hh, g)                                              \
  do {                                                                  \
    _Pragma("unroll") for (int j = 0; j < 8; ++j) {                     \
      float prs = fmaf((float)R[j], 2.0f, br2);                         \
      float pzs = fmaf((float)Z[j], -1.0f, nbz);                        \
      float ph2 = (float)Hh[j] * 2.0f;                                  \
      float er = __expf(fmaf(h, mrc, prs));                             \
      float r  = fmaf(-2.0f, rcpf(er + 1.0f), 2.0f);                    \
      float ez = __expf(fmaf(h, mzc, pzs));                             \
      float z  = rcpf(1.0f + ez);                                       \
      float h2 = h + h;                                                 \
      float ec = __expf(fmaf(r, h2, ph2));                              \
      float cd = fmaf(-2.0f, rcpf(ec + 1.0f), 1.0f);                    \
      h = fmaf(z, h - cd, cd);                                          \
      op[(size_t)((g) * 8 + j) << 9] = h;                               \
    }                                                                   \
  } while (0)

  LOADG(Ar, Az, Ah, 0);
  LOADG(Br_, Bz_, Bh_, 1);
  LOADG(Cr, Cz, Ch, 2);
  for (int g = 0; g < 64; g += 4) {
    LOADG(Dr, Dz, Dh, g + 3);
    STEP8(Ar, Az, Ah, g);
    if (g + 4 < 64) LOADG(Ar, Az, Ah, g + 4);
    STEP8(Br_, Bz_, Bh_, g + 1);
    if (g + 5 < 64) LOADG(Br_, Bz_, Bh_, g + 5);
    STEP8(Cr, Cz, Ch, g + 2);
    if (g + 6 < 64) LOADG(Cr, Cz, Ch, g + 6);
    STEP8(Dr, Dz, Dh, g + 3);
  }
#undef LOADG
#undef STEP8
}

// ---------------- launch ----------------
extern "C" void kernel_launch(void* const* d_in, const int* in_sizes, int n_in,
                              void* d_out, int out_size, void* d_ws, size_t ws_size,
                              hipStream_t stream) {
  const float* x  = (const float*)d_in[0];
  const float* h0 = (const float*)d_in[1];
  const float* kr = (const float*)d_in[2];
  const float* kz = (const float*)d_in[3];
  const float* kh = (const float*)d_in[4];
  const float* mr = (const float*)d_in[5];
  const float* mz = (const float*)d_in[6];
  const float* br = (const float*)d_in[7];
  const float* bz = (const float*)d_in[8];
  float* out = (float*)d_out;

  f16* ws = (f16*)d_ws;
  f16* Wtr = ws;
  f16* Wtz = ws + 131072;
  f16* Wth = ws + 262144;

  // per-batch ws need (bytes): x_f16 = 262144, pr/pz/ph = 3*524288 -> 1835008
  size_t avail = ws_size > 786432 ? ws_size - 786432 : 0;
  int Bc = (int)(avail / 1835008ull);
  if (Bc < 1) Bc = 1;
  if (Bc > B_TOT) Bc = B_TOT;

  cvt_w<<<1536, 256, 0, stream>>>(kr, kz, kh, ws);

  for (int b0 = 0; b0 < B_TOT; b0 += Bc) {
    int bc = (Bc < B_TOT - b0) ? Bc : (B_TOT - b0);
    f16* Xf = ws + 393216;
    f16* Pr = Xf + (size_t)bc * 131072;
    f16* Pz = Pr + (size_t)bc * 262144;
    f16* Ph = Pz + (size_t)bc * 262144;

    cvt_x<<<bc * 128, 256, 0, stream>>>(
        (const float4*)(x + (size_t)b0 * 131072), (f16x4*)Xf);
    brc_gemm3<<<bc * 32, 256, 0, stream>>>(Xf, Wtr, Wtz, Wth, Pr, Pz, Ph, bc * 4);
    brc_scan<<<bc * 2, 256, 0, stream>>>(Pr, Pz, Ph, h0, mr, mz, br, bz, out, b0);
  }
}

// Round 3
// 197.973 us; speedup vs baseline: 1.2319x; 1.2319x over previous
//
#include <hip/hip_runtime.h>

typedef _Float16 f16;
typedef _Float16 f16x8 __attribute__((ext_vector_type(8)));
typedef _Float16 f16x4 __attribute__((ext_vector_type(4)));
typedef float f32x4 __attribute__((ext_vector_type(4)));

#define B_TOT 128
#define T_LEN 512
#define D_DIM 256
#define H_DIM 512

// ---------------- helpers ----------------
__device__ __forceinline__ void gload_lds16(const void* g, void* l) {
  __builtin_amdgcn_global_load_lds(
      (const __attribute__((address_space(1))) void*)g,
      (__attribute__((address_space(3))) void*)l, 16, 0, 0);
}

__device__ __forceinline__ float rcpf(float x) { return __builtin_amdgcn_rcpf(x); }

// ---------------- kernel 1: weight convert + transpose ----------------
// W[k][n] f32 (256x512) -> Wt[n][k] f16 (512x256), 3 weights
__global__ void __launch_bounds__(256) cvt_w(const float* __restrict__ Wr,
                                             const float* __restrict__ Wz,
                                             const float* __restrict__ Wh,
                                             f16* __restrict__ Wt) {
  int idx = blockIdx.x * 256 + threadIdx.x;      // < 3*131072
  int w = idx >> 17;
  int rem = idx & 131071;
  int n = rem >> 8;        // 0..511
  int k = rem & 255;       // 0..255
  const float* W = (w == 0) ? Wr : ((w == 1) ? Wz : Wh);
  Wt[(size_t)w * 131072 + n * 256 + k] = (f16)W[k * 512 + n];
}

// ---------------- kernel 2: x convert f32 -> f16 ----------------
__global__ void __launch_bounds__(256) cvt_x(const float4* __restrict__ in,
                                             f16x4* __restrict__ out) {
  int idx = blockIdx.x * 256 + threadIdx.x;
  float4 v = in[idx];
  f16x4 o;
  o[0] = (f16)v.x; o[1] = (f16)v.y; o[2] = (f16)v.z; o[3] = (f16)v.w;
  out[idx] = o;
}

// ---------------- kernel 3: fused 3-weight GEMM ----------------
// X [M][256] f16, Wt [512][256] f16 (pre-transposed).
// P output layout CHUNKED: P[bb][tg(64)][h(512)][8t] f16.
// LDS layout conflict-free k-planes: A [kc(4)][128 rows][8 halfs],
// B per weight [kc(4)][64 rows][8 halfs]. gload_lds dest linear; the k-plane
// permutation is applied on the per-lane GLOBAL source address.
// tile: BM=128 x (BN=64 per weight), BK=32; 256 threads = 4 waves (2x2)
#define BM 128
#define BN 64
#define BK 32

__global__ void __launch_bounds__(256) brc_gemm3(
    const f16* __restrict__ X,
    const f16* __restrict__ Wr, const f16* __restrict__ Wz, const f16* __restrict__ Wh,
    f16* __restrict__ Pr, f16* __restrict__ Pz, f16* __restrict__ Ph,
    int Mtiles) {
  __shared__ f16 lds[4096 + 3 * 2048];   // A 8KB + B 12KB = 20 KiB
  const int tid = threadIdx.x;
  const int wid = tid >> 6, lane = tid & 63;
  // XCD-aware swizzle: consecutive logical ids (which share an X tile) land
  // on the same XCD. nwg = Mtiles*8, always divisible by 8.
  const int bid = blockIdx.x;
  const int lid = (bid & 7) * Mtiles + (bid >> 3);
  const int mt = lid >> 3, nt = lid & 7;   // m-major: 8 consecutive lids share mt
  const int m0 = mt * BM, n0 = nt * BN;
  const int wr = wid >> 1, wc = wid & 1;   // 2x2 wave grid: wave tile 64x32

  f32x4 acc[3][4][2] = {};

  for (int kt = 0; kt < 8; ++kt) {
    const int k0 = kt * BK;
    // ---- stage A: plane kc = wid, halves c=0,1. lane i -> row c*64+i ----
#pragma unroll
    for (int c = 0; c < 2; ++c) {
      const char* g = (const char*)X +
          ((size_t)(m0 + c * 64 + lane)) * 512 + k0 * 2 + wid * 16;
      char* l = (char*)lds + wid * 2048 + c * 1024;   // wave-uniform dest
      gload_lds16(g, l);
    }
    // ---- stage B: entries e = wid*3+j -> (w = e>>2, kc = e&3) ----
#pragma unroll
    for (int j = 0; j < 3; ++j) {
      int e = wid * 3 + j;
      int w = e >> 2, kc = e & 3;
      const f16* W = (w == 0) ? Wr : ((w == 1) ? Wz : Wh);
      const char* g = (const char*)W +
          ((size_t)(n0 + lane)) * 512 + k0 * 2 + kc * 16;
      char* l = (char*)lds + 8192 + w * 4096 + kc * 1024;  // wave-uniform dest
      gload_lds16(g, l);
    }
    __syncthreads();

    const int kcq = lane >> 4;     // this lane's k-plane
    const int rl = lane & 15;
    f16x8 a[4], b[3][2];
#pragma unroll
    for (int mi = 0; mi < 4; ++mi)
      a[mi] = *(const f16x8*)&lds[kcq * 1024 + (wr * 64 + mi * 16 + rl) * 8];
#pragma unroll
    for (int w = 0; w < 3; ++w)
#pragma unroll
      for (int ni = 0; ni < 2; ++ni)
        b[w][ni] = *(const f16x8*)&lds[4096 + w * 2048 + kcq * 512 +
                                       (wc * 32 + ni * 16 + rl) * 8];
#pragma unroll
    for (int w = 0; w < 3; ++w)
#pragma unroll
      for (int mi = 0; mi < 4; ++mi)
#pragma unroll
        for (int ni = 0; ni < 2; ++ni)
          acc[w][mi][ni] = __builtin_amdgcn_mfma_f32_16x16x32_f16(
              a[mi], b[w][ni], acc[w][mi][ni], 0, 0, 0);
    __syncthreads();
  }

  // ---- epilogue: C/D layout col = lane&15, row = (lane>>4)*4 + r ----
  // store to chunked P[bb][tg][h][8t]; one f16x4 per fragment per lane.
  // full wave covers contiguous 256B spans -> perfectly coalesced.
  const int col = lane & 15;
  const int rbase = (lane >> 4) * 4;
#pragma unroll
  for (int w = 0; w < 3; ++w) {
    f16* P = (w == 0) ? Pr : ((w == 1) ? Pz : Ph);
#pragma unroll
    for (int mi = 0; mi < 4; ++mi) {
      int m = m0 + wr * 64 + mi * 16 + rbase;
      int bbl = m >> 9;
      int t = m & 511;
      size_t base = ((size_t)bbl * 64 + (t >> 3)) * 4096 + (t & 7);
#pragma unroll
      for (int ni = 0; ni < 2; ++ni) {
        int hcol = n0 + wc * 32 + ni * 16 + col;
        f16x4 v;
#pragma unroll
        for (int r = 0; r < 4; ++r) v[r] = (f16)acc[w][mi][ni][r];
        *(f16x4*)&P[base + (size_t)hcol * 8] = v;
      }
    }
  }
}

// ---------------- kernel 4: recurrent scan ----------------
// One thread per (batch, hidden) chain. P is [bb][tg][h][8t]: lane i reads
// 16B at stride 16B -> perfectly coalesced. Quad-buffered, 3 groups ahead.
__global__ void __launch_bounds__(256) brc_scan(
    const f16* __restrict__ Pr, const f16* __restrict__ Pz, const f16* __restrict__ Ph,
    const float* __restrict__ h0, const float* __restrict__ mr, const float* __restrict__ mz,
    const float* __restrict__ br, const float* __restrict__ bz,
    float* __restrict__ out, int b0) {
  int gid = blockIdx.x * 256 + threadIdx.x;   // 0 .. bc*512-1
  int bb = gid >> 9;
  int i = gid & 511;
  float h = h0[((size_t)(b0 + bb) << 9) + i];
  // folded constants (see R2):
  float mrc = 2.0f * mr[i], mzc = -mz[i];
  float br2 = 2.0f * br[i], nbz = -bz[i];
  size_t pbase = ((size_t)bb << 18) + (size_t)i * 8;   // bb*64*4096 + i*8 halfs
  const f16* prp = Pr + pbase;
  const f16* pzp = Pz + pbase;
  const f16* php = Ph + pbase;
  float* op = out + (((size_t)(b0 + bb)) << 18) + i;

  f16x8 Ar, Az, Ah, Br_, Bz_, Bh_, Cr, Cz, Ch, Dr, Dz, Dh;

#define LOADG(R, Z, Hh, g)                                              \
  do {                                                                  \
    R  = *(const f16x8*)(prp + ((size_t)(g) << 12));                    \
    Z  = *(const f16x8*)(pzp + ((size_t)(g) << 12));                    \
    Hh = *(const f16x8*)(php + ((size_t)(g) << 12));                    \
  } while (0)

#define STEP8(R, Z, Hh, g)                                              \
  do {                                                                  \
    _Pragma("unroll") for (int j = 0; j < 8; ++j) {                     \
      float prs = fmaf((float)R[j], 2.0f, br2);                         \
      float pzs = fmaf((float)Z[j], -1.0f, nbz);                        \
      float ph2 = (float)Hh[j] * 2.0f;                                  \
      float er = __expf(fmaf(h, mrc, prs));                             \
      float r  = fmaf(-2.0f, rcpf(er + 1.0f), 2.0f);                    \
      float ez = __expf(fmaf(h, mzc, pzs));                             \
      float z  = rcpf(1.0f + ez);                                       \
      float h2 = h + h;                                                 \
      float ec = __expf(fmaf(r, h2, ph2));                              \
      float cd = fmaf(-2.0f, rcpf(ec + 1.0f), 1.0f);                    \
      h = fmaf(z, h - cd, cd);                                          \
      op[(size_t)((g) * 8 + j) << 9] = h;                               \
    }                                                                   \
  } while (0)

  LOADG(Ar, Az, Ah, 0);
  LOADG(Br_, Bz_, Bh_, 1);
  LOADG(Cr, Cz, Ch, 2);
  for (int g = 0; g < 64; g += 4) {
    LOADG(Dr, Dz, Dh, g + 3);
    STEP8(Ar, Az, Ah, g);
    if (g + 4 < 64) LOADG(Ar, Az, Ah, g + 4);
    STEP8(Br_, Bz_, Bh_, g + 1);
    if (g + 5 < 64) LOADG(Br_, Bz_, Bh_, g + 5);
    STEP8(Cr, Cz, Ch, g + 2);
    if (g + 6 < 64) LOADG(Cr, Cz, Ch, g + 6);
    STEP8(Dr, Dz, Dh, g + 3);
  }
#undef LOADG
#undef STEP8
}

// ---------------- launch ----------------
extern "C" void kernel_launch(void* const* d_in, const int* in_sizes, int n_in,
                              void* d_out, int out_size, void* d_ws, size_t ws_size,
                              hipStream_t stream) {
  const float* x  = (const float*)d_in[0];
  const float* h0 = (const float*)d_in[1];
  const float* kr = (const float*)d_in[2];
  const float* kz = (const float*)d_in[3];
  const float* kh = (const float*)d_in[4];
  const float* mr = (const float*)d_in[5];
  const float* mz = (const float*)d_in[6];
  const float* br = (const float*)d_in[7];
  const float* bz = (const float*)d_in[8];
  float* out = (float*)d_out;

  f16* ws = (f16*)d_ws;
  f16* Wtr = ws;
  f16* Wtz = ws + 131072;
  f16* Wth = ws + 262144;

  // per-batch ws need (bytes): x_f16 = 262144, pr/pz/ph = 3*524288 -> 1835008
  size_t avail = ws_size > 786432 ? ws_size - 786432 : 0;
  int Bc = (int)(avail / 1835008ull);
  if (Bc < 1) Bc = 1;
  if (Bc > B_TOT) Bc = B_TOT;

  cvt_w<<<1536, 256, 0, stream>>>(kr, kz, kh, ws);

  for (int b0 = 0; b0 < B_TOT; b0 += Bc) {
    int bc = (Bc < B_TOT - b0) ? Bc : (B_TOT - b0);
    f16* Xf = ws + 393216;
    f16* Pr = Xf + (size_t)bc * 131072;
    f16* Pz = Pr + (size_t)bc * 262144;
    f16* Ph = Pz + (size_t)bc * 262144;

    cvt_x<<<bc * 128, 256, 0, stream>>>(
        (const float4*)(x + (size_t)b0 * 131072), (f16x4*)Xf);
    brc_gemm3<<<bc * 32, 256, 0, stream>>>(Xf, Wtr, Wtz, Wth, Pr, Pz, Ph, bc * 4);
    brc_scan<<<bc * 2, 256, 0, stream>>>(Pr, Pz, Ph, h0, mr, mz, br, bz, out, b0);
  }
}

// Round 4
// 184.667 us; speedup vs baseline: 1.3207x; 1.0721x over previous
//
#include <hip/hip_runtime.h>

typedef _Float16 f16;
typedef _Float16 f16x8 __attribute__((ext_vector_type(8)));
typedef _Float16 f16x4 __attribute__((ext_vector_type(4)));
typedef float f32x4 __attribute__((ext_vector_type(4)));

#define B_TOT 128
#define T_LEN 512
#define D_DIM 256
#define H_DIM 512

// ---------------- helpers ----------------
__device__ __forceinline__ void gload_lds16(const void* g, void* l) {
  __builtin_amdgcn_global_load_lds(
      (const __attribute__((address_space(1))) void*)g,
      (__attribute__((address_space(3))) void*)l, 16, 0, 0);
}

__device__ __forceinline__ float rcpf(float x) { return __builtin_amdgcn_rcpf(x); }

// ---------------- kernel 1: weight convert + transpose ----------------
// W[k][n] f32 (256x512) -> Wt[n][k] f16 (512x256), 3 weights
__global__ void __launch_bounds__(256) cvt_w(const float* __restrict__ Wr,
                                             const float* __restrict__ Wz,
                                             const float* __restrict__ Wh,
                                             f16* __restrict__ Wt) {
  int idx = blockIdx.x * 256 + threadIdx.x;      // < 3*131072
  int w = idx >> 17;
  int rem = idx & 131071;
  int n = rem >> 8;        // 0..511
  int k = rem & 255;       // 0..255
  const float* W = (w == 0) ? Wr : ((w == 1) ? Wz : Wh);
  Wt[(size_t)w * 131072 + n * 256 + k] = (f16)W[k * 512 + n];
}

// ---------------- kernel 2: x convert f32 -> f16 ----------------
__global__ void __launch_bounds__(256) cvt_x(const float4* __restrict__ in,
                                             f16x4* __restrict__ out) {
  int idx = blockIdx.x * 256 + threadIdx.x;
  float4 v = in[idx];
  f16x4 o;
  o[0] = (f16)v.x; o[1] = (f16)v.y; o[2] = (f16)v.z; o[3] = (f16)v.w;
  out[idx] = o;
}

// ---------------- kernel 3: fused 3-weight GEMM, 2-phase pipelined ----------------
// X [M][256] f16, Wt [512][256] f16 (pre-transposed).
// P output layout CHUNKED: P[bb][tg(64)][h(512)][8t] f16.
// BM=128, BN=64 (x3 weights), BK=64, 4 K-iterations, double-buffered LDS.
// LDS per buffer (40 KB): A [p(8)][128 rows][16B], B [w(3)][p(8)][64 cols][16B].
// k-plane p covers k = p*8..p*8+7 within the 64-wide K tile; plane for MFMA
// sub-step kk and lane quad kq=(lane>>4) is p = kk*4+kq.
__global__ void __launch_bounds__(256, 2) brc_gemm3(
    const f16* __restrict__ X,
    const f16* __restrict__ Wr, const f16* __restrict__ Wz, const f16* __restrict__ Wh,
    f16* __restrict__ Pr, f16* __restrict__ Pz, f16* __restrict__ Ph,
    int Mtiles) {
  __shared__ char lds[81920];          // 2 x 40 KB buffers
  const int tid = threadIdx.x;
  const int wid = tid >> 6, lane = tid & 63;
  // bijective XCD swizzle; consecutive lids (sharing an X tile) on one XCD
  const int bid = blockIdx.x;
  const int lid = (bid & 7) * Mtiles + (bid >> 3);   // grid = Mtiles*8
  const int mt = lid >> 3, nt = lid & 7;             // m-major
  const int m0 = mt * 128, n0 = nt * 64;
  const int wr = wid >> 1, wc = wid & 1;             // 2x2 waves, tile 64x32

  const char* Xc  = (const char*)X + (size_t)m0 * 512;
  const char* WrC = (const char*)Wr + (size_t)n0 * 512;
  const char* WzC = (const char*)Wz + (size_t)n0 * 512;
  const char* WhC = (const char*)Wh + (size_t)n0 * 512;

  f32x4 acc[3][4][2] = {};

  // stage K-tile kt into buffer buf: 10 gload_lds per thread
#define STAGE(kt, buf)                                                        \
  do {                                                                        \
    char* lb_ = lds + (buf) * 40960;                                          \
    _Pragma("unroll") for (int c = 0; c < 4; ++c) {  /* A: 16 chunks */       \
      int id_ = c * 4 + wid, p_ = id_ >> 1, rh_ = id_ & 1;                    \
      gload_lds16(Xc + ((size_t)(rh_ * 64 + lane)) * 512 + (kt) * 128 + p_ * 16, \
                  lb_ + p_ * 2048 + rh_ * 1024);                              \
    }                                                                         \
    _Pragma("unroll") for (int c = 0; c < 6; ++c) {  /* B: 24 chunks */       \
      int id_ = c * 4 + wid, w3_ = id_ >> 3, p_ = id_ & 7;                    \
      const char* W_ = (w3_ == 0) ? WrC : ((w3_ == 1) ? WzC : WhC);           \
      gload_lds16(W_ + (size_t)lane * 512 + (kt) * 128 + p_ * 16,             \
                  lb_ + 16384 + w3_ * 8192 + p_ * 1024);                      \
    }                                                                         \
  } while (0)

  STAGE(0, 0);
  __syncthreads();

  const int kq = lane >> 4, rl = lane & 15;
  for (int kt = 0; kt < 4; ++kt) {
    if (kt < 3) STAGE(kt + 1, (kt + 1) & 1);       // prefetch BEFORE compute
    const char* lb = lds + (kt & 1) * 40960;
#pragma unroll
    for (int kk = 0; kk < 2; ++kk) {
      f16x8 a[4], b[3][2];
#pragma unroll
      for (int mi = 0; mi < 4; ++mi)
        a[mi] = *(const f16x8*)(lb + (kk * 4 + kq) * 2048 +
                                (wr * 64 + mi * 16 + rl) * 16);
#pragma unroll
      for (int w = 0; w < 3; ++w)
#pragma unroll
        for (int ni = 0; ni < 2; ++ni)
          b[w][ni] = *(const f16x8*)(lb + 16384 + w * 8192 + (kk * 4 + kq) * 1024 +
                                     (wc * 32 + ni * 16 + rl) * 16);
#pragma unroll
      for (int w = 0; w < 3; ++w)
#pragma unroll
        for (int mi = 0; mi < 4; ++mi)
#pragma unroll
          for (int ni = 0; ni < 2; ++ni)
            acc[w][mi][ni] = __builtin_amdgcn_mfma_f32_16x16x32_f16(
                a[mi], b[w][ni], acc[w][mi][ni], 0, 0, 0);
    }
    __syncthreads();   // drains vmcnt(0): next tile ready; buffers safe to swap
  }
#undef STAGE

  // ---- epilogue: C/D layout col = lane&15, row = (lane>>4)*4 + r ----
  // store to chunked P[bb][tg][h][8t]; one f16x4 per fragment per lane.
  const int col = lane & 15;
  const int rbase = (lane >> 4) * 4;
#pragma unroll
  for (int w = 0; w < 3; ++w) {
    f16* P = (w == 0) ? Pr : ((w == 1) ? Pz : Ph);
#pragma unroll
    for (int mi = 0; mi < 4; ++mi) {
      int m = m0 + wr * 64 + mi * 16 + rbase;
      int bbl = m >> 9;
      int t = m & 511;
      size_t base = ((size_t)bbl * 64 + (t >> 3)) * 4096 + (t & 7);
#pragma unroll
      for (int ni = 0; ni < 2; ++ni) {
        int hcol = n0 + wc * 32 + ni * 16 + col;
        f16x4 v;
#pragma unroll
        for (int r = 0; r < 4; ++r) v[r] = (f16)acc[w][mi][ni][r];
        *(f16x4*)&P[base + (size_t)hcol * 8] = v;
      }
    }
  }
}

// ---------------- kernel 4: recurrent scan ----------------
// One thread per (batch, hidden) chain. P is [bb][tg][h][8t]: lane i reads
// 16B at stride 16B -> perfectly coalesced. Quad-buffered, 3 groups ahead.
__global__ void __launch_bounds__(256) brc_scan(
    const f16* __restrict__ Pr, const f16* __restrict__ Pz, const f16* __restrict__ Ph,
    const float* __restrict__ h0, const float* __restrict__ mr, const float* __restrict__ mz,
    const float* __restrict__ br, const float* __restrict__ bz,
    float* __restrict__ out, int b0) {
  int gid = blockIdx.x * 256 + threadIdx.x;   // 0 .. bc*512-1
  int bb = gid >> 9;
  int i = gid & 511;
  float h = h0[((size_t)(b0 + bb) << 9) + i];
  // folded constants (see R2):
  float mrc = 2.0f * mr[i], mzc = -mz[i];
  float br2 = 2.0f * br[i], nbz = -bz[i];
  size_t pbase = ((size_t)bb << 18) + (size_t)i * 8;   // bb*64*4096 + i*8 halfs
  const f16* prp = Pr + pbase;
  const f16* pzp = Pz + pbase;
  const f16* php = Ph + pbase;
  float* op = out + (((size_t)(b0 + bb)) << 18) + i;

  f16x8 Ar, Az, Ah, Br_, Bz_, Bh_, Cr, Cz, Ch, Dr, Dz, Dh;

#define LOADG(R, Z, Hh, g)                                              \
  do {                                                                  \
    R  = *(const f16x8*)(prp + ((size_t)(g) << 12));                    \
    Z  = *(const f16x8*)(pzp + ((size_t)(g) << 12));                    \
    Hh = *(const f16x8*)(php + ((size_t)(g) << 12));                    \
  } while (0)

#define STEP8(R, Z, Hh, g)                                              \
  do {                                                                  \
    _Pragma("unroll") for (int j = 0; j < 8; ++j) {                     \
      float prs = fmaf((float)R[j], 2.0f, br2);                         \
      float pzs = fmaf((float)Z[j], -1.0f, nbz);                        \
      float ph2 = (float)Hh[j] * 2.0f;                                  \
      float er = __expf(fmaf(h, mrc, prs));                             \
      float r  = fmaf(-2.0f, rcpf(er + 1.0f), 2.0f);                    \
      float ez = __expf(fmaf(h, mzc, pzs));                             \
      float z  = rcpf(1.0f + ez);                                       \
      float h2 = h + h;                                                 \
      float ec = __expf(fmaf(r, h2, ph2));                              \
      float cd = fmaf(-2.0f, rcpf(ec + 1.0f), 1.0f);                    \
      h = fmaf(z, h - cd, cd);                                          \
      op[(size_t)((g) * 8 + j) << 9] = h;                               \
    }                                                                   \
  } while (0)

  LOADG(Ar, Az, Ah, 0);
  LOADG(Br_, Bz_, Bh_, 1);
  LOADG(Cr, Cz, Ch, 2);
  for (int g = 0; g < 64; g += 4) {
    LOADG(Dr, Dz, Dh, g + 3);
    STEP8(Ar, Az, Ah, g);
    if (g + 4 < 64) LOADG(Ar, Az, Ah, g + 4);
    STEP8(Br_, Bz_, Bh_, g + 1);
    if (g + 5 < 64) LOADG(Br_, Bz_, Bh_, g + 5);
    STEP8(Cr, Cz, Ch, g + 2);
    if (g + 6 < 64) LOADG(Cr, Cz, Ch, g + 6);
    STEP8(Dr, Dz, Dh, g + 3);
  }
#undef LOADG
#undef STEP8
}

// ---------------- launch ----------------
extern "C" void kernel_launch(void* const* d_in, const int* in_sizes, int n_in,
                              void* d_out, int out_size, void* d_ws, size_t ws_size,
                              hipStream_t stream) {
  const float* x  = (const float*)d_in[0];
  const float* h0 = (const float*)d_in[1];
  const float* kr = (const float*)d_in[2];
  const float* kz = (const float*)d_in[3];
  const float* kh = (const float*)d_in[4];
  const float* mr = (const float*)d_in[5];
  const float* mz = (const float*)d_in[6];
  const float* br = (const float*)d_in[7];
  const float* bz = (const float*)d_in[8];
  float* out = (float*)d_out;

  f16* ws = (f16*)d_ws;
  f16* Wtr = ws;
  f16* Wtz = ws + 131072;
  f16* Wth = ws + 262144;

  // per-batch ws need (bytes): x_f16 = 262144, pr/pz/ph = 3*524288 -> 1835008
  size_t avail = ws_size > 786432 ? ws_size - 786432 : 0;
  int Bc = (int)(avail / 1835008ull);
  if (Bc < 1) Bc = 1;
  if (Bc > B_TOT) Bc = B_TOT;

  cvt_w<<<1536, 256, 0, stream>>>(kr, kz, kh, ws);

  for (int b0 = 0; b0 < B_TOT; b0 += Bc) {
    int bc = (Bc < B_TOT - b0) ? Bc : (B_TOT - b0);
    f16* Xf = ws + 393216;
    f16* Pr = Xf + (size_t)bc * 131072;
    f16* Pz = Pr + (size_t)bc * 262144;
    f16* Ph = Pz + (size_t)bc * 262144;

    cvt_x<<<bc * 128, 256, 0, stream>>>(
        (const float4*)(x + (size_t)b0 * 131072), (f16x4*)Xf);
    brc_gemm3<<<bc * 32, 256, 0, stream>>>(Xf, Wtr, Wtz, Wth, Pr, Pz, Ph, bc * 4);
    brc_scan<<<bc * 2, 256, 0, stream>>>(Pr, Pz, Ph, h0, mr, mz, br, bz, out, b0);
  }
}